// Round 6
// baseline (2038.382 us; speedup 1.0000x reference)
//
#include <hip/hip_runtime.h>

#define NC 512
#define WSZ 64
#define RH 4
#define BA 16
#define TS 32
#define IFSZ 471
#define EPSC 1e-8f

// ---------- helpers ----------
__device__ __forceinline__ float wave_sum(float v) {
#pragma unroll
  for (int m = 32; m >= 1; m >>= 1) v += __shfl_xor(v, m, 64);
  return v;
}
__device__ __forceinline__ float wave_max(float v) {
#pragma unroll
  for (int m = 32; m >= 1; m >>= 1) v = fmaxf(v, __shfl_xor(v, m, 64));
  return v;
}
__device__ __forceinline__ float block_sum(float v, float* s_red, int tid) {
  float w = wave_sum(v);
  if ((tid & 63) == 0) s_red[tid >> 6] = w;
  __syncthreads();
  float tot = 0.f;
#pragma unroll
  for (int i = 0; i < 8; i++) tot += s_red[i];
  __syncthreads();
  return tot;
}
__device__ __forceinline__ float softplus_f(float x) {
  return fmaxf(x, 0.f) + log1pf(expf(-fabsf(x)));
}
__device__ __forceinline__ float sigmoid_f(float x) {
  return 1.f / (1.f + expf(-x));
}

// ---------- init ----------
__global__ void init_kernel(float* link, float* mem, float* us, float* pr,
                            float* ppb, float* rwi, float* wcwi) {
  size_t i = (size_t)blockIdx.x * blockDim.x + threadIdx.x;
  size_t stride = (size_t)gridDim.x * blockDim.x;
  for (size_t x = i; x < (size_t)BA * NC * NC; x += stride) link[x] = 0.f;
  for (size_t x = i; x < (size_t)BA * NC * WSZ; x += stride) mem[x] = 0.f;
  for (size_t x = i; x < (size_t)BA * RH * NC; x += stride) rwi[x] = 1.f / NC;
  for (size_t x = i; x < (size_t)BA * NC; x += stride) {
    us[x] = 0.f; pr[x] = 0.f; wcwi[x] = 1.f / NC;
  }
  // ppb layout [s][b][n]: slice product over j in [32s,32s+32) with u==0:
  // factor 0 taken iff exists j<n in slice, i.e. n > 32s
  for (size_t x = i; x < (size_t)16 * BA * NC; x += stride) {
    int s = (int)(x / (BA * NC));
    int n = (int)(x % NC);
    ppb[x] = (n > 32 * s) ? 0.f : 1.f;
  }
}

// ---------- interface GEMM + activations (once) ----------
__global__ __launch_bounds__(512) void iface_kernel(
    const float* __restrict__ ctrl, const float* __restrict__ W,
    const float* __restrict__ bif, float* __restrict__ iface) {
  int bt = blockIdx.x;
  int tid = threadIdx.x;
  __shared__ float s_ctrl[512];
  __shared__ float s_v[IFSZ];
  s_ctrl[tid] = ctrl[(size_t)bt * 512 + tid];
  __syncthreads();
  if (tid < IFSZ) {
    float acc = bif[tid];
#pragma unroll 8
    for (int k = 0; k < 512; k++) acc = fmaf(s_ctrl[k], W[(size_t)k * IFSZ + tid], acc);
    s_v[tid] = acc;
  }
  __syncthreads();
  if (tid < IFSZ) {
    float v = s_v[tid];
    float o;
    if (tid < 256) o = v;
    else if (tid < 260) o = softplus_f(v);
    else if (tid < 324) o = v;
    else if (tid < 325) o = softplus_f(v);
    else if (tid < 389) o = sigmoid_f(v);
    else if (tid < 453) o = v;
    else if (tid < 459) o = sigmoid_f(v);
    else {
      int g = (tid - 459) / 3;
      int base = 459 + g * 3;
      float a = s_v[base], b = s_v[base + 1], c = s_v[base + 2];
      float mx = fmaxf(a, fmaxf(b, c));
      float ea = expf(a - mx), eb = expf(b - mx), ec = expf(c - mx);
      o = expf(v - mx) / (ea + eb + ec);
    }
    iface[(size_t)bt * IFSZ + tid] = o;
  }
}

// ---------- fused per-step kernel ----------
__global__ __launch_bounds__(512, 1) void fused_step(
    const float* __restrict__ iface,
    const float* __restrict__ mem_cur, float* __restrict__ mem_nxt,
    const float* __restrict__ us_old, float* __restrict__ us_new,
    const float* __restrict__ pr_old, float* __restrict__ pr_new,
    const float* __restrict__ ppb_old, float* __restrict__ ppb_new,
    const float* __restrict__ fwd_old, float* __restrict__ fwd_new,
    const float* __restrict__ bwd_old, float* __restrict__ bwd_new,
    const float* __restrict__ opP_old, float* __restrict__ opP_new,
    const float* __restrict__ rw_init, const float* __restrict__ wcw_init,
    float* __restrict__ link, float* __restrict__ out, int t) {
  const int stripe = blockIdx.x, b = blockIdx.y;
  const int tid = threadIdx.x, lane = tid & 63, wid = tid >> 6;
  const int n = tid;
  const size_t bn = (size_t)b * NC;
  const float* ifcA = iface + ((size_t)b * TS + t) * IFSZ;
  const float* ifcB = ifcA - IFSZ;  // only deref'd when t>0

  __shared__ float s_keys[5][64];
  __shared__ float s_e[64], s_v[64];
  __shared__ float s_rw4[4][NC];
  __shared__ float s_ww[NC], s_prec[NC], s_unew[NC];
  __shared__ float s_redA[8][5], s_redB[8][5];
  __shared__ float s_part[8][4][64];
  __shared__ float s_bpB[4][4][NC];
  __shared__ float s_red[8];

  // ---- entry: finalize out(t-2) from previous kernel's partials (stripe 1) ----
  if (stripe == 1 && t >= 2 && tid < 256) {
    float s = 0.f;
#pragma unroll
    for (int ss = 0; ss < 16; ss++)
      s += opP_old[((size_t)ss * BA + b) * (RH * WSZ) + tid];
    int r = tid >> 6, w = tid & 63;
    out[(((size_t)b * TS + (t - 2)) * RH + r) * WSZ + w] = s;
  }

  // ---- entry: prefetch all independent global data (one latency wall) ----
  const int i0 = stripe * 32 + wid * 4;
  float* lbase = link + (size_t)b * NC * NC;
  float lreg[4][8];
#pragma unroll
  for (int rr = 0; rr < 4; rr++)
#pragma unroll
    for (int jj = 0; jj < 8; jj++)
      lreg[rr][jj] = lbase[(size_t)(i0 + rr) * NC + jj * 64 + lane];

  float mo4[4];
  {
    const float* ms = mem_cur + bn * WSZ + (size_t)stripe * 32 * WSZ;
#pragma unroll
    for (int kk = 0; kk < 4; kk++) mo4[kk] = ms[tid + kk * 512];
  }
  float u_n = us_old[bn + n];
  float pr_n = pr_old[bn + n];
  float pp = 1.f;
#pragma unroll
  for (int s = 0; s < 16; s++) pp *= ppb_old[((size_t)s * BA + b) * NC + n];

  // key / erase / write-vector staging (wave-parallel)
  if (t > 0 && wid < 4) {
    float k = ifcB[wid * 64 + lane];
    float ss = wave_sum(k * k);
    s_keys[wid][lane] = k * rsqrtf(ss + EPSC);
  } else if (t > 0 && wid == 4) {
    float k = ifcA[260 + lane];
    float ss = wave_sum(k * k);
    s_keys[4][lane] = k * rsqrtf(ss + EPSC);
  } else if (wid == 5) {
    s_e[lane] = ifcA[325 + lane];
  } else if (wid == 6) {
    s_v[lane] = ifcA[389 + lane];
  }

  // phase-B inputs (coalesced loads, accumulated to limit VGPR)
  float4 m4[16];
  float bs4[4] = {0.f, 0.f, 0.f, 0.f};
  float f4[4];
  float rwreg[4];
  float wcw;
  if (t > 0) {
    const float4* mrow = (const float4*)(mem_cur + (bn + n) * WSZ);
#pragma unroll
    for (int i = 0; i < 16; i++) m4[i] = mrow[i];
#pragma unroll
    for (int r = 0; r < 4; r++) {
#pragma unroll
      for (int s = 0; s < 16; s++)
        bs4[r] += bwd_old[(((size_t)s * BA + b) * RH + r) * NC + n];
      f4[r] = fwd_old[((size_t)b * RH + r) * NC + n];
    }
  } else {
#pragma unroll
    for (int r = 0; r < 4; r++) rwreg[r] = rw_init[((size_t)b * RH + r) * NC + n];
    wcw = wcw_init[bn + n];
  }
  __syncthreads();  // S1

  // ================= phase B: rw(t-1) recomputed locally =================
  if (t > 0) {
    float msum = 0.f, d0 = 0.f, d1 = 0.f, d2 = 0.f, d3 = 0.f, dw = 0.f;
#pragma unroll
    for (int i = 0; i < 16; i++) {
      float4 mm = m4[i];
      msum = fmaf(mm.x, mm.x, fmaf(mm.y, mm.y, fmaf(mm.z, mm.z, fmaf(mm.w, mm.w, msum))));
      d0 = fmaf(mm.x, s_keys[0][4 * i], fmaf(mm.y, s_keys[0][4 * i + 1],
           fmaf(mm.z, s_keys[0][4 * i + 2], fmaf(mm.w, s_keys[0][4 * i + 3], d0))));
      d1 = fmaf(mm.x, s_keys[1][4 * i], fmaf(mm.y, s_keys[1][4 * i + 1],
           fmaf(mm.z, s_keys[1][4 * i + 2], fmaf(mm.w, s_keys[1][4 * i + 3], d1))));
      d2 = fmaf(mm.x, s_keys[2][4 * i], fmaf(mm.y, s_keys[2][4 * i + 1],
           fmaf(mm.z, s_keys[2][4 * i + 2], fmaf(mm.w, s_keys[2][4 * i + 3], d2))));
      d3 = fmaf(mm.x, s_keys[3][4 * i], fmaf(mm.y, s_keys[3][4 * i + 1],
           fmaf(mm.z, s_keys[3][4 * i + 2], fmaf(mm.w, s_keys[3][4 * i + 3], d3))));
      dw = fmaf(mm.x, s_keys[4][4 * i], fmaf(mm.y, s_keys[4][4 * i + 1],
           fmaf(mm.z, s_keys[4][4 * i + 2], fmaf(mm.w, s_keys[4][4 * i + 3], dw))));
    }
    float minv = rsqrtf(msum + EPSC);
    float sim[5];
    sim[0] = d0 * minv * ifcB[256];
    sim[1] = d1 * minv * ifcB[257];
    sim[2] = d2 * minv * ifcB[258];
    sim[3] = d3 * minv * ifcB[259];
    sim[4] = dw * minv * ifcA[324];
#pragma unroll
    for (int i = 0; i < 5; i++) {
      float wm = wave_max(sim[i]);
      if (lane == 0) s_redA[wid][i] = wm;
    }
    __syncthreads();  // S2
    float ex[5];
#pragma unroll
    for (int i = 0; i < 5; i++) {
      float mx = s_redA[0][i];
#pragma unroll
      for (int w = 1; w < 8; w++) mx = fmaxf(mx, s_redA[w][i]);
      ex[i] = expf(sim[i] - mx);
      float ws_ = wave_sum(ex[i]);
      if (lane == 0) s_redB[wid][i] = ws_;
    }
    __syncthreads();  // S3
    float den[5];
#pragma unroll
    for (int i = 0; i < 5; i++) {
      float s = 0.f;
#pragma unroll
      for (int w = 0; w < 8; w++) s += s_redB[w][i];
      den[i] = s;
    }
    wcw = ex[4] / den[4];
#pragma unroll
    for (int r = 0; r < 4; r++) {
      float rcw = ex[r] / den[r];
      float m0 = ifcB[459 + r * 3], m1 = ifcB[459 + r * 3 + 1], m2 = ifcB[459 + r * 3 + 2];
      rwreg[r] = fmaf(m0, bs4[r], fmaf(m1, rcw, m2 * f4[r]));
    }
  }

  // ---- publish per-step shared state ----
#pragma unroll
  for (int r = 0; r < 4; r++) s_rw4[r][n] = rwreg[r];
  float allocv = (1.f - u_n) * pp;
  float ag = ifcA[457], wg = ifcA[458];
  float wwn = wg * (ag * allocv + (1.f - ag) * wcw);
  s_ww[n] = wwn;
  s_prec[n] = pr_n;
  float u = u_n + wwn - u_n * wwn;
  float psi = 1.f;
#pragma unroll
  for (int r = 0; r < 4; r++) psi *= (1.f - ifcA[453 + r] * rwreg[r]);
  float unew = u * psi;
  s_unew[n] = unew;
  __syncthreads();  // S4

  // ---- read-words partials for out(t-1): this stripe's 32 rows ----
  if (t > 0) {
    float p0 = 0.f, p1 = 0.f, p2 = 0.f, p3 = 0.f;
#pragma unroll
    for (int kk = 0; kk < 4; kk++) {
      int row = stripe * 32 + wid + kk * 8;
      float m = mo4[kk];
      p0 = fmaf(s_rw4[0][row], m, p0);
      p1 = fmaf(s_rw4[1][row], m, p1);
      p2 = fmaf(s_rw4[2][row], m, p2);
      p3 = fmaf(s_rw4[3][row], m, p3);
    }
    s_part[wid][0][lane] = p0;
    s_part[wid][1][lane] = p1;
    s_part[wid][2][lane] = p2;
    s_part[wid][3][lane] = p3;
  }

  // ================= phase A: link update + fwd/bwd =================
  float wsi[4], rwi4[4][4];
#pragma unroll
  for (int rr = 0; rr < 4; rr++) {
    wsi[rr] = s_ww[i0 + rr];
#pragma unroll
    for (int r = 0; r < 4; r++) rwi4[rr][r] = s_rw4[r][i0 + rr];
  }
  float facc[4][4];
  float bc[4][8];
#pragma unroll
  for (int a = 0; a < 4; a++)
#pragma unroll
    for (int c = 0; c < 4; c++) facc[a][c] = 0.f;
#pragma unroll
  for (int a = 0; a < 4; a++)
#pragma unroll
    for (int c = 0; c < 8; c++) bc[a][c] = 0.f;

#pragma unroll
  for (int jj = 0; jj < 8; jj++) {
    int j = jj * 64 + lane;
    float swj = s_ww[j], spj = s_prec[j];
    float srw0 = s_rw4[0][j], srw1 = s_rw4[1][j], srw2 = s_rw4[2][j], srw3 = s_rw4[3][j];
#pragma unroll
    for (int rr = 0; rr < 4; rr++) {
      float ln = fmaf(1.f - wsi[rr] - swj, lreg[rr][jj], wsi[rr] * spj);
      if (j == i0 + rr) ln = 0.f;
      lbase[(size_t)(i0 + rr) * NC + j] = ln;
      facc[rr][0] = fmaf(ln, srw0, facc[rr][0]);
      facc[rr][1] = fmaf(ln, srw1, facc[rr][1]);
      facc[rr][2] = fmaf(ln, srw2, facc[rr][2]);
      facc[rr][3] = fmaf(ln, srw3, facc[rr][3]);
      bc[0][jj] = fmaf(ln, rwi4[rr][0], bc[0][jj]);
      bc[1][jj] = fmaf(ln, rwi4[rr][1], bc[1][jj]);
      bc[2][jj] = fmaf(ln, rwi4[rr][2], bc[2][jj]);
      bc[3][jj] = fmaf(ln, rwi4[rr][3], bc[3][jj]);
    }
  }
#pragma unroll
  for (int rr = 0; rr < 4; rr++) {
#pragma unroll
    for (int r = 0; r < 4; r++) facc[rr][r] = wave_sum(facc[rr][r]);
    if (lane == 0) {
#pragma unroll
      for (int r = 0; r < 4; r++)
        fwd_new[((size_t)b * RH + r) * NC + (i0 + rr)] = facc[rr][r];
    }
  }
  // bwd 2-round LDS tree
  if (wid >= 4) {
#pragma unroll
    for (int r = 0; r < 4; r++)
#pragma unroll
      for (int jj = 0; jj < 8; jj++) s_bpB[wid - 4][r][jj * 64 + lane] = bc[r][jj];
  }
  __syncthreads();  // S5
  if (wid < 4) {
#pragma unroll
    for (int r = 0; r < 4; r++)
#pragma unroll
      for (int jj = 0; jj < 8; jj++) s_bpB[wid][r][jj * 64 + lane] += bc[r][jj];
  }
  __syncthreads();  // S6
#pragma unroll
  for (int r = 0; r < 4; r++) {
    float a = (s_bpB[0][r][tid] + s_bpB[1][r][tid]) + (s_bpB[2][r][tid] + s_bpB[3][r][tid]);
    bwd_new[(((size_t)stripe * BA + b) * RH + r) * NC + tid] = a;
  }
  // read-words partial across waves -> global (consumed next kernel), coalesced
  if (t > 0 && tid < 256) {
    float a = 0.f;
    int r = tid >> 6, w = tid & 63;
#pragma unroll
    for (int wv = 0; wv < 8; wv++) a += s_part[wv][r][w];
    opP_new[((size_t)stripe * BA + b) * (RH * WSZ) + tid] = a;
  }
  // memory erase+write for this stripe's 32 rows
  {
    float* mnb = mem_nxt + bn * WSZ + (size_t)stripe * 32 * WSZ;
#pragma unroll
    for (int kk = 0; kk < 4; kk++) {
      int flat = tid + kk * 512;
      int row = stripe * 32 + wid + kk * 8;
      mnb[flat] = fmaf(mo4[kk], 1.f - s_ww[row] * s_e[lane], s_ww[row] * s_v[lane]);
    }
  }
  // allocation slice partial product for step t+1 (coalesced [s][b][n])
  {
    float pslice = 1.f;
    int base0 = stripe * 32;
#pragma unroll
    for (int jj = 0; jj < 32; jj++) {
      int j = base0 + jj;
      float uj = s_unew[j];
      bool take = (uj < unew) || (uj == unew && j < n);
      pslice *= take ? uj : 1.f;
    }
    ppb_new[((size_t)stripe * BA + b) * NC + n] = pslice;
  }
  // usage + precedence (stripe 15)
  if (stripe == 15) {
    us_new[bn + n] = unew;
    float sw = block_sum(wwn, s_red, tid);
    pr_new[bn + n] = (1.f - sw) * pr_n + wwn;
  }
}

// ---------- final read step (t = 31) + finalize out(30) ----------
__global__ __launch_bounds__(512) void final_read(
    const float* __restrict__ iface, const float* __restrict__ mem_cur,
    const float* __restrict__ fwd_old, const float* __restrict__ bwd_old,
    const float* __restrict__ opP_old, float* __restrict__ out) {
  const int r = blockIdx.x, b = blockIdx.y;
  const int tid = threadIdx.x, lane = tid & 63, wid = tid >> 6;
  const int n = tid;
  const int t = TS - 1;
  const size_t bn = (size_t)b * NC;
  const float* ifc = iface + ((size_t)b * TS + t) * IFSZ;
  __shared__ float s_k[64];
  __shared__ float s_rw[NC];
  __shared__ float s_part[8][64];
  __shared__ float s_red[8];

  if (r == 0 && tid < 256) {
    float s = 0.f;
#pragma unroll
    for (int ss = 0; ss < 16; ss++)
      s += opP_old[((size_t)ss * BA + b) * (RH * WSZ) + tid];
    int rr = tid >> 6, w = tid & 63;
    out[(((size_t)b * TS + (TS - 2)) * RH + rr) * WSZ + w] = s;
  }

  if (wid == 0) {
    float k = ifc[r * 64 + lane];
    float ss = wave_sum(k * k);
    s_k[lane] = k * rsqrtf(ss + EPSC);
  }
  __syncthreads();

  const float4* mrow = (const float4*)(mem_cur + (bn + n) * WSZ);
  float msum = 0.f, dot = 0.f;
#pragma unroll
  for (int i = 0; i < 16; i++) {
    float4 m4 = mrow[i];
    msum = fmaf(m4.x, m4.x, fmaf(m4.y, m4.y, fmaf(m4.z, m4.z, fmaf(m4.w, m4.w, msum))));
    dot = fmaf(m4.x, s_k[4 * i], fmaf(m4.y, s_k[4 * i + 1],
          fmaf(m4.z, s_k[4 * i + 2], fmaf(m4.w, s_k[4 * i + 3], dot))));
  }
  float sim = dot * rsqrtf(msum + EPSC) * ifc[256 + r];
  float wm = wave_max(sim);
  if (lane == 0) s_red[wid] = wm;
  __syncthreads();
  float mx = s_red[0];
#pragma unroll
  for (int i = 1; i < 8; i++) mx = fmaxf(mx, s_red[i]);
  __syncthreads();
  float e = expf(sim - mx);
  float ssum = block_sum(e, s_red, tid);
  float rcw = e / ssum;
  float bs = 0.f;
#pragma unroll
  for (int s = 0; s < 16; s++)
    bs += bwd_old[(((size_t)s * BA + b) * RH + r) * NC + n];
  float f = fwd_old[((size_t)b * RH + r) * NC + n];
  float m0 = ifc[459 + r * 3], m1 = ifc[459 + r * 3 + 1], m2 = ifc[459 + r * 3 + 2];
  s_rw[n] = fmaf(m0, bs, fmaf(m1, rcw, m2 * f));
  __syncthreads();

  float acc = 0.f;
  const float* mb = mem_cur + bn * WSZ;
#pragma unroll 8
  for (int k = 0; k < 64; k++) {
    int nn = wid * 64 + k;
    acc = fmaf(s_rw[nn], mb[(size_t)nn * WSZ + lane], acc);
  }
  s_part[wid][lane] = acc;
  __syncthreads();
  if (tid < 64) {
    float a = 0.f;
#pragma unroll
    for (int w = 0; w < 8; w++) a += s_part[w][tid];
    out[(((size_t)b * TS + t) * RH + r) * WSZ + tid] = a;
  }
}

// ---------- host ----------
extern "C" void kernel_launch(void* const* d_in, const int* in_sizes, int n_in,
                              void* d_out, int out_size, void* d_ws, size_t ws_size,
                              hipStream_t stream) {
  const float* ctrl = (const float*)d_in[0];
  const float* Wif = (const float*)d_in[1];
  const float* bif = (const float*)d_in[2];
  float* out = (float*)d_out;

  float* p = (float*)d_ws;
  float* link = p;    p += (size_t)BA * NC * NC;
  float* mem0 = p;    p += (size_t)BA * NC * WSZ;
  float* mem1 = p;    p += (size_t)BA * NC * WSZ;
  float* iface = p;   p += (size_t)BA * TS * IFSZ;
  float* us0 = p;     p += (size_t)BA * NC;
  float* us1 = p;     p += (size_t)BA * NC;
  float* pr0 = p;     p += (size_t)BA * NC;
  float* pr1 = p;     p += (size_t)BA * NC;
  float* ppb0 = p;    p += (size_t)16 * BA * NC;
  float* ppb1 = p;    p += (size_t)16 * BA * NC;
  float* fwd0 = p;    p += (size_t)BA * RH * NC;
  float* fwd1 = p;    p += (size_t)BA * RH * NC;
  float* bwd0 = p;    p += (size_t)16 * BA * RH * NC;
  float* bwd1 = p;    p += (size_t)16 * BA * RH * NC;
  float* opP0 = p;    p += (size_t)16 * BA * RH * WSZ;
  float* opP1 = p;    p += (size_t)16 * BA * RH * WSZ;
  float* rwi = p;     p += (size_t)BA * RH * NC;
  float* wcwi = p;    p += (size_t)BA * NC;

  float* mem[2] = {mem0, mem1};
  float* us[2] = {us0, us1};
  float* pr[2] = {pr0, pr1};
  float* ppb[2] = {ppb0, ppb1};
  float* fwd[2] = {fwd0, fwd1};
  float* bwd[2] = {bwd0, bwd1};
  float* opP[2] = {opP0, opP1};

  hipLaunchKernelGGL(init_kernel, dim3(2048), dim3(256), 0, stream,
                     link, mem0, us0, pr0, ppb0, rwi, wcwi);
  hipLaunchKernelGGL(iface_kernel, dim3(BA * TS), dim3(512), 0, stream,
                     ctrl, Wif, bif, iface);
  for (int t = 0; t < TS; t++) {
    int rd = t & 1, wr = rd ^ 1;
    hipLaunchKernelGGL(fused_step, dim3(16, BA), dim3(512), 0, stream,
                       iface, mem[rd], mem[wr], us[rd], us[wr], pr[rd], pr[wr],
                       ppb[rd], ppb[wr], fwd[rd], fwd[wr], bwd[rd], bwd[wr],
                       opP[rd], opP[wr], rwi, wcwi, link, out, t);
  }
  // after t=31: latest state in index (32)&1 = 0
  hipLaunchKernelGGL(final_read, dim3(RH, BA), dim3(512), 0, stream,
                     iface, mem[0], fwd[0], bwd[0], opP[0], out);
}

// Round 7
// 1435.329 us; speedup vs baseline: 1.4201x; 1.4201x over previous
//
#include <hip/hip_runtime.h>

#define NC 512
#define WSZ 64
#define RH 4
#define BA 16
#define TS 32
#define IFSZ 471
#define EPSC 1e-8f

// ---------- helpers ----------
__device__ __forceinline__ float wave_sum(float v) {
#pragma unroll
  for (int m = 32; m >= 1; m >>= 1) v += __shfl_xor(v, m, 64);
  return v;
}
__device__ __forceinline__ float wave_max(float v) {
#pragma unroll
  for (int m = 32; m >= 1; m >>= 1) v = fmaxf(v, __shfl_xor(v, m, 64));
  return v;
}
__device__ __forceinline__ float block_sum(float v, float* s_red, int tid) {
  float w = wave_sum(v);
  if ((tid & 63) == 0) s_red[tid >> 6] = w;
  __syncthreads();
  float tot = 0.f;
#pragma unroll
  for (int i = 0; i < 8; i++) tot += s_red[i];
  __syncthreads();
  return tot;
}
__device__ __forceinline__ float softplus_f(float x) {
  return fmaxf(x, 0.f) + log1pf(expf(-fabsf(x)));
}
__device__ __forceinline__ float sigmoid_f(float x) {
  return 1.f / (1.f + expf(-x));
}

// ---------- init ----------
__global__ void init_kernel(float* link, float* mem, float* us, float* pr,
                            float* ppb, float* rwi, float* wcwi) {
  size_t i = (size_t)blockIdx.x * blockDim.x + threadIdx.x;
  size_t stride = (size_t)gridDim.x * blockDim.x;
  for (size_t x = i; x < (size_t)BA * NC * NC; x += stride) link[x] = 0.f;
  for (size_t x = i; x < (size_t)BA * NC * WSZ; x += stride) mem[x] = 0.f;
  for (size_t x = i; x < (size_t)BA * RH * NC; x += stride) rwi[x] = 1.f / NC;
  for (size_t x = i; x < (size_t)BA * NC; x += stride) {
    us[x] = 0.f; pr[x] = 0.f; wcwi[x] = 1.f / NC;
  }
  // ppb layout [s][b][n]: slice product over j in [32s,32s+32) with u==0:
  // factor 0 taken iff exists j<n in slice, i.e. n > 32s
  for (size_t x = i; x < (size_t)16 * BA * NC; x += stride) {
    int s = (int)(x / (BA * NC));
    int n = (int)(x % NC);
    ppb[x] = (n > 32 * s) ? 0.f : 1.f;
  }
}

// ---------- interface GEMM + activations (once) ----------
__global__ __launch_bounds__(512) void iface_kernel(
    const float* __restrict__ ctrl, const float* __restrict__ W,
    const float* __restrict__ bif, float* __restrict__ iface) {
  int bt = blockIdx.x;
  int tid = threadIdx.x;
  __shared__ float s_ctrl[512];
  __shared__ float s_v[IFSZ];
  s_ctrl[tid] = ctrl[(size_t)bt * 512 + tid];
  __syncthreads();
  if (tid < IFSZ) {
    float acc = bif[tid];
#pragma unroll 8
    for (int k = 0; k < 512; k++) acc = fmaf(s_ctrl[k], W[(size_t)k * IFSZ + tid], acc);
    s_v[tid] = acc;
  }
  __syncthreads();
  if (tid < IFSZ) {
    float v = s_v[tid];
    float o;
    if (tid < 256) o = v;
    else if (tid < 260) o = softplus_f(v);
    else if (tid < 324) o = v;
    else if (tid < 325) o = softplus_f(v);
    else if (tid < 389) o = sigmoid_f(v);
    else if (tid < 453) o = v;
    else if (tid < 459) o = sigmoid_f(v);
    else {
      int g = (tid - 459) / 3;
      int base = 459 + g * 3;
      float a = s_v[base], b = s_v[base + 1], c = s_v[base + 2];
      float mx = fmaxf(a, fmaxf(b, c));
      float ea = expf(a - mx), eb = expf(b - mx), ec = expf(c - mx);
      o = expf(v - mx) / (ea + eb + ec);
    }
    iface[(size_t)bt * IFSZ + tid] = o;
  }
}

// ---------- fused per-step kernel ----------
// grid = dim3(BA, 16): b = blockIdx.x, stripe = blockIdx.y
// => flat id = stripe*16 + b => XCD = flat % 8 = b % 8: each batch's 16 blocks
//    stay on ONE XCD; its link slice + state (~1.6 MB) is L2-resident across launches.
__global__ __launch_bounds__(512) void fused_step(
    const float* __restrict__ iface,
    const float* __restrict__ mem_cur, float* __restrict__ mem_nxt,
    const float* __restrict__ us_old, float* __restrict__ us_new,
    const float* __restrict__ pr_old, float* __restrict__ pr_new,
    const float* __restrict__ ppb_old, float* __restrict__ ppb_new,
    const float* __restrict__ fwd_old, float* __restrict__ fwd_new,
    const float* __restrict__ bwd_old, float* __restrict__ bwd_new,
    const float* __restrict__ opP_old, float* __restrict__ opP_new,
    const float* __restrict__ rw_init, const float* __restrict__ wcw_init,
    float* __restrict__ link, float* __restrict__ out, int t) {
  const int b = blockIdx.x, stripe = blockIdx.y;
  const int tid = threadIdx.x, lane = tid & 63, wid = tid >> 6;
  const int n = tid;
  const size_t bn = (size_t)b * NC;
  const float* ifcA = iface + ((size_t)b * TS + t) * IFSZ;
  const float* ifcB = ifcA - IFSZ;  // only deref'd when t>0

  __shared__ float s_keys[5][64];
  __shared__ float s_e[64], s_v[64];
  __shared__ float s_rw4[4][NC];
  __shared__ float s_ww[NC], s_prec[NC], s_unew[NC];
  __shared__ float s_redA[8][5], s_redB[8][5];
  __shared__ float s_part[8][4][64];
  __shared__ float s_bpB[4][4][NC];
  __shared__ float s_red[8];

  // ---- entry: finalize out(t-2) from previous kernel's partials (stripe 1) ----
  if (stripe == 1 && t >= 2 && tid < 256) {
    float s = 0.f;
#pragma unroll
    for (int ss = 0; ss < 16; ss++)
      s += opP_old[((size_t)ss * BA + b) * (RH * WSZ) + tid];
    int r = tid >> 6, w = tid & 63;
    out[(((size_t)b * TS + (t - 2)) * RH + r) * WSZ + w] = s;
  }

  // ---- entry: prefetch small independent global data ----
  float mo4[4];
  {
    const float* ms = mem_cur + bn * WSZ + (size_t)stripe * 32 * WSZ;
#pragma unroll
    for (int kk = 0; kk < 4; kk++) mo4[kk] = ms[tid + kk * 512];
  }
  float u_n = us_old[bn + n];
  float pr_n = pr_old[bn + n];
  float pp = 1.f;
#pragma unroll
  for (int s = 0; s < 16; s++) pp *= ppb_old[((size_t)s * BA + b) * NC + n];

  // key / erase / write-vector staging (wave-parallel)
  if (t > 0 && wid < 4) {
    float k = ifcB[wid * 64 + lane];
    float ss = wave_sum(k * k);
    s_keys[wid][lane] = k * rsqrtf(ss + EPSC);
  } else if (t > 0 && wid == 4) {
    float k = ifcA[260 + lane];
    float ss = wave_sum(k * k);
    s_keys[4][lane] = k * rsqrtf(ss + EPSC);
  } else if (wid == 5) {
    s_e[lane] = ifcA[325 + lane];
  } else if (wid == 6) {
    s_v[lane] = ifcA[389 + lane];
  }

  // phase-B inputs (coalesced loads, accumulated to limit VGPR)
  float4 m4[16];
  float bs4[4] = {0.f, 0.f, 0.f, 0.f};
  float f4[4];
  float rwreg[4];
  float wcw;
  if (t > 0) {
    const float4* mrow = (const float4*)(mem_cur + (bn + n) * WSZ);
#pragma unroll
    for (int i = 0; i < 16; i++) m4[i] = mrow[i];
#pragma unroll
    for (int r = 0; r < 4; r++) {
#pragma unroll
      for (int s = 0; s < 16; s++)
        bs4[r] += bwd_old[(((size_t)s * BA + b) * RH + r) * NC + n];
      f4[r] = fwd_old[((size_t)b * RH + r) * NC + n];
    }
  } else {
#pragma unroll
    for (int r = 0; r < 4; r++) rwreg[r] = rw_init[((size_t)b * RH + r) * NC + n];
    wcw = wcw_init[bn + n];
  }
  __syncthreads();  // S1

  // ================= phase B: rw(t-1) recomputed locally =================
  if (t > 0) {
    float msum = 0.f, d0 = 0.f, d1 = 0.f, d2 = 0.f, d3 = 0.f, dw = 0.f;
#pragma unroll
    for (int i = 0; i < 16; i++) {
      float4 mm = m4[i];
      msum = fmaf(mm.x, mm.x, fmaf(mm.y, mm.y, fmaf(mm.z, mm.z, fmaf(mm.w, mm.w, msum))));
      d0 = fmaf(mm.x, s_keys[0][4 * i], fmaf(mm.y, s_keys[0][4 * i + 1],
           fmaf(mm.z, s_keys[0][4 * i + 2], fmaf(mm.w, s_keys[0][4 * i + 3], d0))));
      d1 = fmaf(mm.x, s_keys[1][4 * i], fmaf(mm.y, s_keys[1][4 * i + 1],
           fmaf(mm.z, s_keys[1][4 * i + 2], fmaf(mm.w, s_keys[1][4 * i + 3], d1))));
      d2 = fmaf(mm.x, s_keys[2][4 * i], fmaf(mm.y, s_keys[2][4 * i + 1],
           fmaf(mm.z, s_keys[2][4 * i + 2], fmaf(mm.w, s_keys[2][4 * i + 3], d2))));
      d3 = fmaf(mm.x, s_keys[3][4 * i], fmaf(mm.y, s_keys[3][4 * i + 1],
           fmaf(mm.z, s_keys[3][4 * i + 2], fmaf(mm.w, s_keys[3][4 * i + 3], d3))));
      dw = fmaf(mm.x, s_keys[4][4 * i], fmaf(mm.y, s_keys[4][4 * i + 1],
           fmaf(mm.z, s_keys[4][4 * i + 2], fmaf(mm.w, s_keys[4][4 * i + 3], dw))));
    }
    float minv = rsqrtf(msum + EPSC);
    float sim[5];
    sim[0] = d0 * minv * ifcB[256];
    sim[1] = d1 * minv * ifcB[257];
    sim[2] = d2 * minv * ifcB[258];
    sim[3] = d3 * minv * ifcB[259];
    sim[4] = dw * minv * ifcA[324];
#pragma unroll
    for (int i = 0; i < 5; i++) {
      float wm = wave_max(sim[i]);
      if (lane == 0) s_redA[wid][i] = wm;
    }
    __syncthreads();  // S2
    float ex[5];
#pragma unroll
    for (int i = 0; i < 5; i++) {
      float mx = s_redA[0][i];
#pragma unroll
      for (int w = 1; w < 8; w++) mx = fmaxf(mx, s_redA[w][i]);
      ex[i] = expf(sim[i] - mx);
      float ws_ = wave_sum(ex[i]);
      if (lane == 0) s_redB[wid][i] = ws_;
    }
    __syncthreads();  // S3
    float den[5];
#pragma unroll
    for (int i = 0; i < 5; i++) {
      float s = 0.f;
#pragma unroll
      for (int w = 0; w < 8; w++) s += s_redB[w][i];
      den[i] = s;
    }
    wcw = ex[4] / den[4];
#pragma unroll
    for (int r = 0; r < 4; r++) {
      float rcw = ex[r] / den[r];
      float m0 = ifcB[459 + r * 3], m1 = ifcB[459 + r * 3 + 1], m2 = ifcB[459 + r * 3 + 2];
      rwreg[r] = fmaf(m0, bs4[r], fmaf(m1, rcw, m2 * f4[r]));
    }
  }

  // ---- publish per-step shared state ----
#pragma unroll
  for (int r = 0; r < 4; r++) s_rw4[r][n] = rwreg[r];
  float allocv = (1.f - u_n) * pp;
  float ag = ifcA[457], wg = ifcA[458];
  float wwn = wg * (ag * allocv + (1.f - ag) * wcw);
  s_ww[n] = wwn;
  s_prec[n] = pr_n;
  float u = u_n + wwn - u_n * wwn;
  float psi = 1.f;
#pragma unroll
  for (int r = 0; r < 4; r++) psi *= (1.f - ifcA[453 + r] * rwreg[r]);
  float unew = u * psi;
  s_unew[n] = unew;
  __syncthreads();  // S4

  // ---- read-words partials for out(t-1): this stripe's 32 rows ----
  if (t > 0) {
    float p0 = 0.f, p1 = 0.f, p2 = 0.f, p3 = 0.f;
#pragma unroll
    for (int kk = 0; kk < 4; kk++) {
      int row = stripe * 32 + wid + kk * 8;
      float m = mo4[kk];
      p0 = fmaf(s_rw4[0][row], m, p0);
      p1 = fmaf(s_rw4[1][row], m, p1);
      p2 = fmaf(s_rw4[2][row], m, p2);
      p3 = fmaf(s_rw4[3][row], m, p3);
    }
    s_part[wid][0][lane] = p0;
    s_part[wid][1][lane] = p1;
    s_part[wid][2][lane] = p2;
    s_part[wid][3][lane] = p3;
  }

  // ================= phase A: link update + fwd/bwd (streamed, no lreg) =================
  const int i0 = stripe * 32 + wid * 4;
  float wsi[4], rwi4[4][4];
#pragma unroll
  for (int rr = 0; rr < 4; rr++) {
    wsi[rr] = s_ww[i0 + rr];
#pragma unroll
    for (int r = 0; r < 4; r++) rwi4[rr][r] = s_rw4[r][i0 + rr];
  }
  float facc[4][4];
  float bc[4][8];
#pragma unroll
  for (int a = 0; a < 4; a++)
#pragma unroll
    for (int c = 0; c < 4; c++) facc[a][c] = 0.f;
#pragma unroll
  for (int a = 0; a < 4; a++)
#pragma unroll
    for (int c = 0; c < 8; c++) bc[a][c] = 0.f;

  float* lbase = link + (size_t)b * NC * NC;
#pragma unroll
  for (int jj = 0; jj < 8; jj++) {
    int j = jj * 64 + lane;
    float swj = s_ww[j], spj = s_prec[j];
    float srw0 = s_rw4[0][j], srw1 = s_rw4[1][j], srw2 = s_rw4[2][j], srw3 = s_rw4[3][j];
#pragma unroll
    for (int rr = 0; rr < 4; rr++) {
      float* lp = lbase + (size_t)(i0 + rr) * NC + j;
      float l = *lp;
      float ln = fmaf(1.f - wsi[rr] - swj, l, wsi[rr] * spj);
      if (j == i0 + rr) ln = 0.f;
      *lp = ln;
      facc[rr][0] = fmaf(ln, srw0, facc[rr][0]);
      facc[rr][1] = fmaf(ln, srw1, facc[rr][1]);
      facc[rr][2] = fmaf(ln, srw2, facc[rr][2]);
      facc[rr][3] = fmaf(ln, srw3, facc[rr][3]);
      bc[0][jj] = fmaf(ln, rwi4[rr][0], bc[0][jj]);
      bc[1][jj] = fmaf(ln, rwi4[rr][1], bc[1][jj]);
      bc[2][jj] = fmaf(ln, rwi4[rr][2], bc[2][jj]);
      bc[3][jj] = fmaf(ln, rwi4[rr][3], bc[3][jj]);
    }
  }
#pragma unroll
  for (int rr = 0; rr < 4; rr++) {
#pragma unroll
    for (int r = 0; r < 4; r++) facc[rr][r] = wave_sum(facc[rr][r]);
    if (lane == 0) {
#pragma unroll
      for (int r = 0; r < 4; r++)
        fwd_new[((size_t)b * RH + r) * NC + (i0 + rr)] = facc[rr][r];
    }
  }
  // bwd 2-round LDS tree
  if (wid >= 4) {
#pragma unroll
    for (int r = 0; r < 4; r++)
#pragma unroll
      for (int jj = 0; jj < 8; jj++) s_bpB[wid - 4][r][jj * 64 + lane] = bc[r][jj];
  }
  __syncthreads();  // S5
  if (wid < 4) {
#pragma unroll
    for (int r = 0; r < 4; r++)
#pragma unroll
      for (int jj = 0; jj < 8; jj++) s_bpB[wid][r][jj * 64 + lane] += bc[r][jj];
  }
  __syncthreads();  // S6
#pragma unroll
  for (int r = 0; r < 4; r++) {
    float a = (s_bpB[0][r][tid] + s_bpB[1][r][tid]) + (s_bpB[2][r][tid] + s_bpB[3][r][tid]);
    bwd_new[(((size_t)stripe * BA + b) * RH + r) * NC + tid] = a;
  }
  // read-words partial across waves -> global (consumed next kernel), coalesced
  if (t > 0 && tid < 256) {
    float a = 0.f;
    int r = tid >> 6, w = tid & 63;
#pragma unroll
    for (int wv = 0; wv < 8; wv++) a += s_part[wv][r][w];
    opP_new[((size_t)stripe * BA + b) * (RH * WSZ) + tid] = a;
  }
  // memory erase+write for this stripe's 32 rows
  {
    float* mnb = mem_nxt + bn * WSZ + (size_t)stripe * 32 * WSZ;
#pragma unroll
    for (int kk = 0; kk < 4; kk++) {
      int flat = tid + kk * 512;
      int row = stripe * 32 + wid + kk * 8;
      mnb[flat] = fmaf(mo4[kk], 1.f - s_ww[row] * s_e[lane], s_ww[row] * s_v[lane]);
    }
  }
  // allocation slice partial product for step t+1 (coalesced [s][b][n])
  {
    float pslice = 1.f;
    int base0 = stripe * 32;
#pragma unroll
    for (int jj = 0; jj < 32; jj++) {
      int j = base0 + jj;
      float uj = s_unew[j];
      bool take = (uj < unew) || (uj == unew && j < n);
      pslice *= take ? uj : 1.f;
    }
    ppb_new[((size_t)stripe * BA + b) * NC + n] = pslice;
  }
  // usage + precedence (stripe 15)
  if (stripe == 15) {
    us_new[bn + n] = unew;
    float sw = block_sum(wwn, s_red, tid);
    pr_new[bn + n] = (1.f - sw) * pr_n + wwn;
  }
}

// ---------- final read step (t = 31) + finalize out(30) ----------
// grid = dim3(BA, RH): b = blockIdx.x, r = blockIdx.y (keeps batch->XCD pinning)
__global__ __launch_bounds__(512) void final_read(
    const float* __restrict__ iface, const float* __restrict__ mem_cur,
    const float* __restrict__ fwd_old, const float* __restrict__ bwd_old,
    const float* __restrict__ opP_old, float* __restrict__ out) {
  const int b = blockIdx.x, r = blockIdx.y;
  const int tid = threadIdx.x, lane = tid & 63, wid = tid >> 6;
  const int n = tid;
  const int t = TS - 1;
  const size_t bn = (size_t)b * NC;
  const float* ifc = iface + ((size_t)b * TS + t) * IFSZ;
  __shared__ float s_k[64];
  __shared__ float s_rw[NC];
  __shared__ float s_part[8][64];
  __shared__ float s_red[8];

  if (r == 0 && tid < 256) {
    float s = 0.f;
#pragma unroll
    for (int ss = 0; ss < 16; ss++)
      s += opP_old[((size_t)ss * BA + b) * (RH * WSZ) + tid];
    int rr = tid >> 6, w = tid & 63;
    out[(((size_t)b * TS + (TS - 2)) * RH + rr) * WSZ + w] = s;
  }

  if (wid == 0) {
    float k = ifc[r * 64 + lane];
    float ss = wave_sum(k * k);
    s_k[lane] = k * rsqrtf(ss + EPSC);
  }
  __syncthreads();

  const float4* mrow = (const float4*)(mem_cur + (bn + n) * WSZ);
  float msum = 0.f, dot = 0.f;
#pragma unroll
  for (int i = 0; i < 16; i++) {
    float4 m4 = mrow[i];
    msum = fmaf(m4.x, m4.x, fmaf(m4.y, m4.y, fmaf(m4.z, m4.z, fmaf(m4.w, m4.w, msum))));
    dot = fmaf(m4.x, s_k[4 * i], fmaf(m4.y, s_k[4 * i + 1],
          fmaf(m4.z, s_k[4 * i + 2], fmaf(m4.w, s_k[4 * i + 3], dot))));
  }
  float sim = dot * rsqrtf(msum + EPSC) * ifc[256 + r];
  float wm = wave_max(sim);
  if (lane == 0) s_red[wid] = wm;
  __syncthreads();
  float mx = s_red[0];
#pragma unroll
  for (int i = 1; i < 8; i++) mx = fmaxf(mx, s_red[i]);
  __syncthreads();
  float e = expf(sim - mx);
  float ssum = block_sum(e, s_red, tid);
  float rcw = e / ssum;
  float bs = 0.f;
#pragma unroll
  for (int s = 0; s < 16; s++)
    bs += bwd_old[(((size_t)s * BA + b) * RH + r) * NC + n];
  float f = fwd_old[((size_t)b * RH + r) * NC + n];
  float m0 = ifc[459 + r * 3], m1 = ifc[459 + r * 3 + 1], m2 = ifc[459 + r * 3 + 2];
  s_rw[n] = fmaf(m0, bs, fmaf(m1, rcw, m2 * f));
  __syncthreads();

  float acc = 0.f;
  const float* mb = mem_cur + bn * WSZ;
#pragma unroll 8
  for (int k = 0; k < 64; k++) {
    int nn = wid * 64 + k;
    acc = fmaf(s_rw[nn], mb[(size_t)nn * WSZ + lane], acc);
  }
  s_part[wid][lane] = acc;
  __syncthreads();
  if (tid < 64) {
    float a = 0.f;
#pragma unroll
    for (int w = 0; w < 8; w++) a += s_part[w][tid];
    out[(((size_t)b * TS + t) * RH + r) * WSZ + tid] = a;
  }
}

// ---------- host ----------
extern "C" void kernel_launch(void* const* d_in, const int* in_sizes, int n_in,
                              void* d_out, int out_size, void* d_ws, size_t ws_size,
                              hipStream_t stream) {
  const float* ctrl = (const float*)d_in[0];
  const float* Wif = (const float*)d_in[1];
  const float* bif = (const float*)d_in[2];
  float* out = (float*)d_out;

  float* p = (float*)d_ws;
  float* link = p;    p += (size_t)BA * NC * NC;
  float* mem0 = p;    p += (size_t)BA * NC * WSZ;
  float* mem1 = p;    p += (size_t)BA * NC * WSZ;
  float* iface = p;   p += (size_t)BA * TS * IFSZ;
  float* us0 = p;     p += (size_t)BA * NC;
  float* us1 = p;     p += (size_t)BA * NC;
  float* pr0 = p;     p += (size_t)BA * NC;
  float* pr1 = p;     p += (size_t)BA * NC;
  float* ppb0 = p;    p += (size_t)16 * BA * NC;
  float* ppb1 = p;    p += (size_t)16 * BA * NC;
  float* fwd0 = p;    p += (size_t)BA * RH * NC;
  float* fwd1 = p;    p += (size_t)BA * RH * NC;
  float* bwd0 = p;    p += (size_t)16 * BA * RH * NC;
  float* bwd1 = p;    p += (size_t)16 * BA * RH * NC;
  float* opP0 = p;    p += (size_t)16 * BA * RH * WSZ;
  float* opP1 = p;    p += (size_t)16 * BA * RH * WSZ;
  float* rwi = p;     p += (size_t)BA * RH * NC;
  float* wcwi = p;    p += (size_t)BA * NC;

  float* mem[2] = {mem0, mem1};
  float* us[2] = {us0, us1};
  float* pr[2] = {pr0, pr1};
  float* ppb[2] = {ppb0, ppb1};
  float* fwd[2] = {fwd0, fwd1};
  float* bwd[2] = {bwd0, bwd1};
  float* opP[2] = {opP0, opP1};

  hipLaunchKernelGGL(init_kernel, dim3(2048), dim3(256), 0, stream,
                     link, mem0, us0, pr0, ppb0, rwi, wcwi);
  hipLaunchKernelGGL(iface_kernel, dim3(BA * TS), dim3(512), 0, stream,
                     ctrl, Wif, bif, iface);
  for (int t = 0; t < TS; t++) {
    int rd = t & 1, wr = rd ^ 1;
    hipLaunchKernelGGL(fused_step, dim3(BA, 16), dim3(512), 0, stream,
                       iface, mem[rd], mem[wr], us[rd], us[wr], pr[rd], pr[wr],
                       ppb[rd], ppb[wr], fwd[rd], fwd[wr], bwd[rd], bwd[wr],
                       opP[rd], opP[wr], rwi, wcwi, link, out, t);
  }
  // after t=31: latest state in index (32)&1 = 0
  hipLaunchKernelGGL(final_read, dim3(BA, RH), dim3(512), 0, stream,
                     iface, mem[0], fwd[0], bwd[0], opP[0], out);
}